// Round 4
// baseline (304.354 us; speedup 1.0000x reference)
//
#include <hip/hip_runtime.h>
#include <hip/hip_bf16.h>
#include <math.h>

#define EPSV 1e-6f
#define LAMBDAV 1e-3f
#define LN_2PI 1.8378770664093453f

// Kernel 1: v[k, i2, c, q] = sum_p p_in[n0+k, i2, p] * w[i2, c, p, q], fp32.
// grid = 288 (one block per i2); each block loops over the n-chunk.
__global__ __launch_bounds__(256)
void conv_v_kernel(const float* __restrict__ x, const float* __restrict__ w,
                   float* __restrict__ vout, int n0, int cnt)
{
    __shared__ float w_s[32 * 264];   // [c][p*16+q], stride 264
    __shared__ float pv[16];
    __shared__ int pci[16], prow[16], pcol[16];

    const int i2  = blockIdx.x;
    const int tid = threadIdx.x;

    const float* wbase = w + (size_t)i2 * 8192;
    for (int t = tid; t < 8192; t += 256)
        w_s[(t >> 8) * 264 + (t & 255)] = wbase[t];

    if (tid < 16) {
        // invert reference reshape scramble:
        // g = i2*16 + p ; k2 = g>>9 ; c2 = g&511 ; f = k2*544 + c2 = ci*9 + kk
        int e  = i2 * 16 + tid;
        int k2 = e >> 9;
        int c2 = e & 511;
        int f  = k2 * 544 + c2;
        int ci = f / 9;
        int kk = f - ci * 9;
        pci[tid]  = ci;
        prow[tid] = kk / 3 - 1;            // kh - pad
        pcol[tid] = kk - (kk / 3) * 3 - 1; // kw - pad
    }
    __syncthreads();

    const int c1 = tid >> 4, q1 = tid & 15;
    for (int k = 0; k < cnt; ++k) {
        const int nn = n0 + k;
        const int bi = nn >> 6, oi = (nn >> 3) & 7, oj = nn & 7;
        if (tid < 16) {
            int row = 2 * oi + prow[tid];
            int col = 2 * oj + pcol[tid];
            float val = 0.0f;
            if ((unsigned)row < 16u && (unsigned)col < 16u)
                val = x[((bi * 16 + row) * 16 + col) * 544 + pci[tid]];
            pv[tid] = val;
        }
        __syncthreads();

        float acc0 = 0.f, acc1 = 0.f;
        const float* wr0 = &w_s[c1 * 264 + q1];
        const float* wr1 = &w_s[(c1 + 16) * 264 + q1];
        #pragma unroll
        for (int p = 0; p < 16; ++p) {
            float pvp = pv[p];
            acc0 += pvp * wr0[p * 16];
            acc1 += pvp * wr1[p * 16];
        }
        float* vp = vout + ((size_t)k * 288 + i2) * 512;
        vp[tid]       = acc0;
        vp[tid + 256] = acc1;
        __syncthreads();
    }
}

// Kernel 2: EM routing, literal two-pass mu/sigma. One block per position.
__global__ __launch_bounds__(512)
void em_routing_kernel(const float* __restrict__ x,
                       const float* __restrict__ v,
                       const float* __restrict__ beta_u,
                       const float* __restrict__ beta_a,
                       float* __restrict__ out, int n0)
{
    __shared__ float r_s[288 * 33];   // r / rr / ln_ap, stride 33
    __shared__ float a_s[288];
    __shared__ float rsum_s[32];
    __shared__ float mu_s[32 * 17];   // odd stride: conflict-free c-varying reads
    __shared__ float i2ss_s[32 * 17];
    __shared__ float hlog_s[32 * 17];
    __shared__ float aout_s[32];
    __shared__ float kc_s[32];

    const int n   = n0 + blockIdx.x;
    const int tid = threadIdx.x;
    const int bi = n >> 6, oi = (n >> 3) & 7, oj = n & 7;

    if (tid < 288) {
        // a_in gather: c2 in [512,544)
        int k2 = tid >> 5;
        int c2 = 512 + (tid & 31);
        int f  = k2 * 544 + c2;
        int ci = f / 9;
        int kk = f - ci * 9;
        int row = 2 * oi + kk / 3 - 1;
        int col = 2 * oj + (kk - (kk / 3) * 3) - 1;
        float val = 0.f;
        if ((unsigned)row < 16u && (unsigned)col < 16u)
            val = x[((bi * 16 + row) * 16 + col) * 544 + ci];
        a_s[tid] = val;
        for (int c = 0; c < 32; ++c) r_s[tid * 33 + c] = 1.0f / 32.0f;
    }
    __syncthreads();

    const float* vb = v + (size_t)blockIdx.x * 288 * 512;
    const int cc = tid >> 4, qq = tid & 15;

    for (int t = 0; t < 3; ++t) {
        // rr = r*a ; rr /= (sum_c rr + eps)
        if (tid < 288) {
            float a = a_s[tid];
            float ssum = 0.f;
            float* rrow = &r_s[tid * 33];
            for (int c = 0; c < 32; ++c) { float tv = rrow[c] * a; rrow[c] = tv; ssum += tv; }
            float inv = 1.0f / (ssum + EPSV);
            for (int c = 0; c < 32; ++c) rrow[c] *= inv;
        }
        __syncthreads();

        // r_sum[c] = sum_i rr[i][c]
        if (tid < 32) {
            float s = 0.f;
            for (int i = 0; i < 288; ++i) s += r_s[i * 33 + tid];
            rsum_s[tid] = s;
        }
        __syncthreads();

        const float invr = 1.0f / (rsum_s[cc] + EPSV);

        // mu pass (literal)
        {
            float s1 = 0.f;
            for (int i = 0; i < 288; ++i) {
                float co = r_s[i * 33 + cc] * invr;
                s1 += co * vb[(size_t)i * 512 + tid];
            }
            mu_s[cc * 17 + qq] = s1;
        }
        __syncthreads();

        // sigma pass (literal)
        {
            float mu = mu_s[cc * 17 + qq];
            float s2 = 0.f;
            for (int i = 0; i < 288; ++i) {
                float co = r_s[i * 33 + cc] * invr;
                float d  = vb[(size_t)i * 512 + tid] - mu;
                s2 += co * d * d;
            }
            float sig = fmaxf(s2 + EPSV, 1e-4f);
            float hl  = 0.5f * logf(sig);
            hlog_s[cc * 17 + qq] = hl;
            i2ss_s[cc * 17 + qq] = 1.0f / (2.0f * sig);
        }
        __syncthreads();

        // a_out + per-c ln_p constant
        if (tid < 32) {
            float cs = 0.f, shl = 0.f;
            float bu = beta_u[tid];
            for (int q = 0; q < 16; ++q) { float hl = hlog_s[tid * 17 + q]; shl += hl; cs += bu + hl; }
            cs *= rsum_s[tid];
            float arg = LAMBDAV * (beta_a[tid] - cs);
            float ao  = 1.0f / (1.0f + expf(-arg));
            ao = fminf(fmaxf(ao, 1e-4f), 1.0f - 1e-4f);
            aout_s[tid] = ao;
            kc_s[tid]   = logf(ao + EPSV) - shl - 8.0f * LN_2PI;
        }
        __syncthreads();

        if (t < 2) {
            // ln_ap[i][c] = kc[c] - sum_q (v-mu)^2/(2ss), overwrite r_s
            for (int it = 0; it < 18; ++it) {
                int idx = it * 512 + tid;
                int i = idx >> 5, c = idx & 31;
                const float* vp = vb + (size_t)i * 512 + c * 16;
                float acc = kc_s[c];
                #pragma unroll
                for (int q = 0; q < 16; ++q) {
                    float d = vp[q] - mu_s[c * 17 + q];
                    acc -= d * d * i2ss_s[c * 17 + q];
                }
                r_s[i * 33 + c] = acc;
            }
            __syncthreads();

            // softmax over c per row i
            if (tid < 288) {
                float* row = &r_s[tid * 33];
                float mx = -1e30f;
                for (int c = 0; c < 32; ++c) mx = fmaxf(mx, row[c]);
                float sum = 0.f;
                for (int c = 0; c < 32; ++c) { float e = expf(row[c] - mx); row[c] = e; sum += e; }
                float inv = 1.0f / sum;
                for (int c = 0; c < 32; ++c) row[c] *= inv;
            }
            __syncthreads();
        }
    }

    // epilogue (fp32 out): p_out [0,65536) | a_out [65536,69632) | out [69632,139264)
    {
        float mu = mu_s[cc * 17 + qq];
        if (isnan(mu)) mu = 0.f;
        mu = fminf(fmaxf(mu, -10000.f), 10000.f);
        out[(size_t)n * 512 + tid] = mu;
        out[69632 + (size_t)n * 544 + tid] = mu;
        if (tid < 32) {
            float ao = aout_s[tid];
            if (isnan(ao)) ao = 0.5f;
            out[65536 + n * 32 + tid] = ao;
            out[69632 + n * 544 + 512 + tid] = ao;
        }
    }
}

extern "C" void kernel_launch(void* const* d_in, const int* in_sizes, int n_in,
                              void* d_out, int out_size, void* d_ws, size_t ws_size,
                              hipStream_t stream) {
    const float* x  = (const float*)d_in[0];
    const float* w  = (const float*)d_in[1];
    const float* bu = (const float*)d_in[2];
    const float* ba = (const float*)d_in[3];
    float* out = (float*)d_out;
    float* v   = (float*)d_ws;

    // chunk over n so fp32 v fits in the workspace (host-side constant branching)
    const size_t per_n = (size_t)288 * 512 * sizeof(float); // 589824 B
    int CN = (int)(ws_size / per_n);
    if (CN < 1)   CN = 1;    // best effort if ws is tiny
    if (CN > 128) CN = 128;

    for (int ncur = 0; ncur < 128; ncur += CN) {
        int cnt = (128 - ncur < CN) ? (128 - ncur) : CN;
        conv_v_kernel<<<dim3(288), dim3(256), 0, stream>>>(x, w, v, ncur, cnt);
        em_routing_kernel<<<dim3(cnt), dim3(512), 0, stream>>>(x, v, bu, ba, out, ncur);
    }
}

// Round 5
// 225.183 us; speedup vs baseline: 1.3516x; 1.3516x over previous
//
#include <hip/hip_runtime.h>
#include <hip/hip_bf16.h>
#include <math.h>

#define EPSV 1e-6f
#define LAMBDAV 1e-3f
#define LN_2PI 1.8378770664093453f

__device__ __forceinline__ float bfu2f(unsigned short u) {
    union { unsigned int i; float f; } x; x.i = ((unsigned int)u) << 16; return x.f;
}
__device__ __forceinline__ float bflo(unsigned int u) {
    union { unsigned int i; float f; } x; x.i = u << 16; return x.f;
}
__device__ __forceinline__ float bfhi(unsigned int u) {
    union { unsigned int i; float f; } x; x.i = u & 0xffff0000u; return x.f;
}

// Kernel 1: v[k, i2, c, q] = sum_p p_in[n0+k, i2, p] * w[i2, c, p, q], bf16 out.
// grid = (288 i2, n-chunks of 16); block = 256. Two barriers per block total.
__global__ __launch_bounds__(256)
void conv_v_kernel(const float* __restrict__ x, const float* __restrict__ w,
                   __hip_bfloat16* __restrict__ vout, int n0, int cnt)
{
    __shared__ float w_s[32 * 264];   // [c][p*16+q], stride 264 (2-way alias = free)
    __shared__ float pv[16 * 16];     // [nb][p] for 16 positions at once

    const int i2  = blockIdx.x;
    const int nb0 = n0 + blockIdx.y * 16;
    const int tid = threadIdx.x;

    const float* wbase = w + (size_t)i2 * 8192;
    for (int t = tid; t < 8192; t += 256)
        w_s[(t >> 8) * 264 + (t & 255)] = wbase[t];

    {
        // each thread gathers one (position, p) patch element
        int p  = tid & 15;
        int nb = tid >> 4;
        // invert reference reshape scramble:
        // g = i2*16 + p ; k2 = g>>9 ; c2 = g&511 ; f = k2*544 + c2 = ci*9 + kk
        int e  = i2 * 16 + p;
        int k2 = e >> 9;
        int c2 = e & 511;
        int f  = k2 * 544 + c2;
        int ci = f / 9;
        int kk = f - ci * 9;
        int nn = nb0 + nb;
        float val = 0.f;
        if (nn < n0 + cnt) {
            int bi = nn >> 6, oi = (nn >> 3) & 7, oj = nn & 7;
            int row = 2 * oi + kk / 3 - 1;
            int col = 2 * oj + (kk - (kk / 3) * 3) - 1;
            if ((unsigned)row < 16u && (unsigned)col < 16u)
                val = x[((bi * 16 + row) * 16 + col) * 544 + ci];
        }
        pv[nb * 16 + p] = val;
    }
    __syncthreads();

    const int c1 = tid >> 4, q1 = tid & 15;
    const float* wr0 = &w_s[c1 * 264 + q1];
    const float* wr1 = &w_s[(c1 + 16) * 264 + q1];
    const int kmax = min(16, n0 + cnt - nb0);
    for (int k = 0; k < kmax; ++k) {
        float acc0 = 0.f, acc1 = 0.f;
        #pragma unroll
        for (int p = 0; p < 16; ++p) {
            float pvp = pv[k * 16 + p];
            acc0 += pvp * wr0[p * 16];
            acc1 += pvp * wr1[p * 16];
        }
        __hip_bfloat16* vp = vout + ((size_t)(nb0 - n0 + k) * 288 + i2) * 512;
        vp[tid]       = __float2bfloat16(acc0);
        vp[tid + 256] = __float2bfloat16(acc1);
    }
}

// Kernel 2: EM routing. One block of 1024 per position; half-wave shuffles for
// row ops; fused one-pass mu/sigma (sig = s2 - s1^2*(2-s0), exact identity).
__global__ __launch_bounds__(1024)
void em_routing_kernel(const float* __restrict__ x,
                       const unsigned short* __restrict__ v,   // bf16 bits
                       const float* __restrict__ beta_u,
                       const float* __restrict__ beta_a,
                       float* __restrict__ out, int n0)
{
    __shared__ float r_s[288 * 33];   // r / rr / ln_ap, stride 33
    __shared__ float a_s[288];
    __shared__ float part_s[32 * 33]; // rsum partials, stride 33
    __shared__ float rsum_s[32];
    __shared__ float mu_s[32 * 17];
    __shared__ float i2ss_s[32 * 17];
    __shared__ float hlog_s[32 * 17];
    __shared__ float aout_s[32];
    __shared__ float kc_s[32];
    __shared__ float p0_s[512], p1_s[512], p2_s[512];

    const int n   = n0 + blockIdx.x;
    const int tid = threadIdx.x;
    const int bi = n >> 6, oi = (n >> 3) & 7, oj = n & 7;

    #pragma unroll
    for (int k = 0; k < 9; ++k) {
        int idx = k * 1024 + tid;
        r_s[(idx >> 5) * 33 + (idx & 31)] = 1.0f / 32.0f;
    }
    if (tid < 288) {
        // a_in gather: c2 in [512,544)
        int k2 = tid >> 5;
        int c2 = 512 + (tid & 31);
        int f  = k2 * 544 + c2;
        int ci = f / 9;
        int kk = f - ci * 9;
        int row = 2 * oi + kk / 3 - 1;
        int col = 2 * oj + (kk - (kk / 3) * 3) - 1;
        float val = 0.f;
        if ((unsigned)row < 16u && (unsigned)col < 16u)
            val = x[((bi * 16 + row) * 16 + col) * 544 + ci];
        a_s[tid] = val;
    }
    __syncthreads();

    const unsigned short* vb = v + (size_t)blockIdx.x * 288 * 512;
    const int lane_c = tid & 31;   // row ops: c lane
    const int row0   = tid >> 5;   // row ops: 32 rows per sweep
    const int cc  = tid >> 5;      // mu pass: c
    const int rem = tid & 31;
    const int hh  = rem >> 4;      // mu pass: i-half
    const int qq  = rem & 15;      // mu pass: q

    for (int t = 0; t < 3; ++t) {
        // rr = r*a ; rr /= (sum_c rr + eps)  — half-wave per row
        #pragma unroll
        for (int k = 0; k < 9; ++k) {
            int i = k * 32 + row0;
            float val = r_s[i * 33 + lane_c] * a_s[i];
            float s = val;
            s += __shfl_xor(s, 1, 32);
            s += __shfl_xor(s, 2, 32);
            s += __shfl_xor(s, 4, 32);
            s += __shfl_xor(s, 8, 32);
            s += __shfl_xor(s, 16, 32);
            r_s[i * 33 + lane_c] = val / (s + EPSV);
        }
        __syncthreads();

        // r_sum[c] = sum_i rr[i][c]: 32 segment partials + shuffle reduce
        {
            int seg = tid >> 5;
            float ps = 0.f;
            #pragma unroll
            for (int k = 0; k < 9; ++k)
                ps += r_s[(seg * 9 + k) * 33 + lane_c];
            part_s[seg * 33 + lane_c] = ps;
        }
        __syncthreads();
        {
            int c = tid >> 5, sg = tid & 31;
            float sv = part_s[sg * 33 + c];
            sv += __shfl_xor(sv, 1, 32);
            sv += __shfl_xor(sv, 2, 32);
            sv += __shfl_xor(sv, 4, 32);
            sv += __shfl_xor(sv, 8, 32);
            sv += __shfl_xor(sv, 16, 32);
            if (sg == 0) rsum_s[c] = sv;
        }
        __syncthreads();

        // fused mu/sigma one-pass, i split across hh
        {
            float invr = 1.0f / (rsum_s[cc] + EPSV);
            float s0 = 0.f, s1 = 0.f, s2 = 0.f;
            const unsigned short* vp = vb + cc * 16 + qq;
            const int ibeg = hh * 144;
            for (int i = ibeg; i < ibeg + 144; ++i) {
                float co = r_s[i * 33 + cc] * invr;
                float vv = bfu2f(vp[(size_t)i * 512]);
                s0 += co;
                s1 += co * vv;
                s2 += co * vv * vv;
            }
            if (hh == 1) {
                p0_s[cc * 16 + qq] = s0;
                p1_s[cc * 16 + qq] = s1;
                p2_s[cc * 16 + qq] = s2;
            }
            __syncthreads();
            if (hh == 0) {
                s0 += p0_s[cc * 16 + qq];
                s1 += p1_s[cc * 16 + qq];
                s2 += p2_s[cc * 16 + qq];
                float mu  = s1;
                float sig = s2 - s1 * s1 * (2.0f - s0);   // == sum co*(v-mu)^2
                sig = fmaxf(sig + EPSV, 1e-4f);
                float hl = 0.5f * logf(sig);
                mu_s[cc * 17 + qq]   = mu;
                hlog_s[cc * 17 + qq] = hl;
                i2ss_s[cc * 17 + qq] = 1.0f / (2.0f * sig);
            }
        }
        __syncthreads();

        // a_out + per-c ln_p constant
        if (tid < 32) {
            float cs = 0.f, shl = 0.f;
            float bu = beta_u[tid];
            #pragma unroll
            for (int q = 0; q < 16; ++q) { float hl = hlog_s[tid * 17 + q]; shl += hl; cs += bu + hl; }
            cs *= rsum_s[tid];
            float arg = LAMBDAV * (beta_a[tid] - cs);
            float ao  = 1.0f / (1.0f + expf(-arg));
            ao = fminf(fmaxf(ao, 1e-4f), 1.0f - 1e-4f);
            aout_s[tid] = ao;
            kc_s[tid]   = logf(ao + EPSV) - shl - 8.0f * LN_2PI;
        }
        __syncthreads();

        if (t < 2) {
            // ln_ap[i][c] = kc[c] - sum_q (v-mu)^2/(2ss), overwrite r_s
            #pragma unroll
            for (int it = 0; it < 9; ++it) {
                int idx = it * 1024 + tid;
                int i = idx >> 5, c = idx & 31;
                const uint4* vp4 = (const uint4*)(vb + (size_t)i * 512 + c * 16);
                uint4 u0 = vp4[0], u1 = vp4[1];
                const float* mrow = &mu_s[c * 17];
                const float* irow = &i2ss_s[c * 17];
                float acc = kc_s[c];
                float d;
                d = bflo(u0.x) - mrow[0];   acc -= d * d * irow[0];
                d = bfhi(u0.x) - mrow[1];   acc -= d * d * irow[1];
                d = bflo(u0.y) - mrow[2];   acc -= d * d * irow[2];
                d = bfhi(u0.y) - mrow[3];   acc -= d * d * irow[3];
                d = bflo(u0.z) - mrow[4];   acc -= d * d * irow[4];
                d = bfhi(u0.z) - mrow[5];   acc -= d * d * irow[5];
                d = bflo(u0.w) - mrow[6];   acc -= d * d * irow[6];
                d = bfhi(u0.w) - mrow[7];   acc -= d * d * irow[7];
                d = bflo(u1.x) - mrow[8];   acc -= d * d * irow[8];
                d = bfhi(u1.x) - mrow[9];   acc -= d * d * irow[9];
                d = bflo(u1.y) - mrow[10];  acc -= d * d * irow[10];
                d = bfhi(u1.y) - mrow[11];  acc -= d * d * irow[11];
                d = bflo(u1.z) - mrow[12];  acc -= d * d * irow[12];
                d = bfhi(u1.z) - mrow[13];  acc -= d * d * irow[13];
                d = bflo(u1.w) - mrow[14];  acc -= d * d * irow[14];
                d = bfhi(u1.w) - mrow[15];  acc -= d * d * irow[15];
                r_s[i * 33 + c] = acc;
            }
            __syncthreads();

            // softmax over c per row — half-wave shuffles
            #pragma unroll
            for (int k = 0; k < 9; ++k) {
                int i = k * 32 + row0;
                float val = r_s[i * 33 + lane_c];
                float mx = val;
                mx = fmaxf(mx, __shfl_xor(mx, 1, 32));
                mx = fmaxf(mx, __shfl_xor(mx, 2, 32));
                mx = fmaxf(mx, __shfl_xor(mx, 4, 32));
                mx = fmaxf(mx, __shfl_xor(mx, 8, 32));
                mx = fmaxf(mx, __shfl_xor(mx, 16, 32));
                float e = expf(val - mx);
                float s = e;
                s += __shfl_xor(s, 1, 32);
                s += __shfl_xor(s, 2, 32);
                s += __shfl_xor(s, 4, 32);
                s += __shfl_xor(s, 8, 32);
                s += __shfl_xor(s, 16, 32);
                r_s[i * 33 + lane_c] = e / s;
            }
            __syncthreads();
        }
    }

    // epilogue (fp32): p_out [0,65536) | a_out [65536,69632) | out [69632,139264)
    if (tid < 512) {
        int c = tid >> 4, q = tid & 15;
        float mu = mu_s[c * 17 + q];
        if (isnan(mu)) mu = 0.f;
        mu = fminf(fmaxf(mu, -10000.f), 10000.f);
        out[(size_t)n * 512 + tid] = mu;
        out[69632 + (size_t)n * 544 + tid] = mu;
        if (tid < 32) {
            float ao = aout_s[tid];
            if (isnan(ao)) ao = 0.5f;
            out[65536 + n * 32 + tid] = ao;
            out[69632 + n * 544 + 512 + tid] = ao;
        }
    }
}

extern "C" void kernel_launch(void* const* d_in, const int* in_sizes, int n_in,
                              void* d_out, int out_size, void* d_ws, size_t ws_size,
                              hipStream_t stream) {
    const float* x  = (const float*)d_in[0];
    const float* w  = (const float*)d_in[1];
    const float* bu = (const float*)d_in[2];
    const float* ba = (const float*)d_in[3];
    float* out = (float*)d_out;
    __hip_bfloat16* v = (__hip_bfloat16*)d_ws;  // bf16 v: 128*288*512*2B = 37.7 MB

    const size_t per_n = (size_t)288 * 512 * sizeof(__hip_bfloat16); // 294912 B
    int CN = (int)(ws_size / per_n);
    if (CN < 1)   CN = 1;
    if (CN > 128) CN = 128;

    for (int ncur = 0; ncur < 128; ncur += CN) {
        int cnt = (128 - ncur < CN) ? (128 - ncur) : CN;
        conv_v_kernel<<<dim3(288, (cnt + 15) / 16), dim3(256), 0, stream>>>(x, w, v, ncur, cnt);
        em_routing_kernel<<<dim3(cnt), dim3(1024), 0, stream>>>(
            x, (const unsigned short*)v, bu, ba, out, ncur);
    }
}